// Round 3
// baseline (3263.383 us; speedup 1.0000x reference)
//
#include <hip/hip_runtime.h>
#include <hip/hip_bf16.h>
#include <stdint.h>

#define NODES 50000
#define RELS  4
#define EDGES 1600000
#define FEAT  256
#define NCLS  16
#define MPAD  50048                 // 391 * 128
#define NBUCK 782                   // ceil(50000 / 64)

typedef __attribute__((ext_vector_type(8))) short short8;
typedef __attribute__((ext_vector_type(8))) unsigned short u16x8;
typedef __attribute__((ext_vector_type(4))) float f32x4;

static __device__ __forceinline__ float bf2f(unsigned short u) {
    return __uint_as_float(((unsigned int)u) << 16);
}
static __device__ __forceinline__ unsigned short f2bf(float f) {
    unsigned int x = __float_as_uint(f);
    unsigned int r = x + 0x7fffu + ((x >> 16) & 1u);
    return (unsigned short)(r >> 16);
}

// ---------------- CSR build ----------------

__global__ void k_hist(const int* __restrict__ edges, int* deg_row, int* deg_col) {
    int idx = blockIdx.x * blockDim.x + threadIdx.x;
    if (idx >= RELS * EDGES) return;
    int r = idx / EDGES;
    int e = idx - r * EDGES;
    const int* base = edges + (size_t)r * 2 * EDGES;
    int row = base[e];
    int col = base[EDGES + e];
    atomicAdd(&deg_row[r * NODES + row], 1);
    atomicAdd(&deg_col[r * NODES + col], 1);
}

__global__ void k_dinv(const int* __restrict__ deg_row, const int* __restrict__ deg_col,
                       float* dinv_row, float* dinv_col) {
    int idx = blockIdx.x * blockDim.x + threadIdx.x;
    if (idx >= RELS * NODES) return;
    int dr = deg_row[idx]; if (dr < 1) dr = 1;
    int dc = deg_col[idx]; if (dc < 1) dc = 1;
    dinv_row[idx] = rsqrtf((float)dr);
    dinv_col[idx] = rsqrtf((float)dc);
}

// one block per relation; Hillis-Steele chunked exclusive scan of deg_row -> row_ptr
__global__ void k_scan(const int* __restrict__ deg_row, int* row_ptr) {
    int r = blockIdx.x;
    int tid = threadIdx.x;
    __shared__ int s[1024];
    int carry = 0;
    for (int base = 0; base < NODES; base += 1024) {
        int i = base + tid;
        int v = (i < NODES) ? deg_row[r * NODES + i] : 0;
        s[tid] = v;
        __syncthreads();
        for (int off = 1; off < 1024; off <<= 1) {
            int t = (tid >= off) ? s[tid - off] : 0;
            __syncthreads();
            s[tid] += t;
            __syncthreads();
        }
        int incl = s[tid];
        if (i < NODES) row_ptr[r * (NODES + 1) + i] = carry + incl - v;
        int tot = s[1023];
        __syncthreads();
        carry += tot;
    }
    if (tid == 0) row_ptr[r * (NODES + 1) + NODES] = carry;
}

// bucket cursors = row_ptr at bucket starts (bucket = 64 consecutive rows)
__global__ void k_binit(const int* __restrict__ row_ptr, int* bcur) {
    int idx = blockIdx.x * blockDim.x + threadIdx.x;
    if (idx >= RELS * NBUCK) return;
    int r = idx / NBUCK;
    int b = idx - r * NBUCK;
    bcur[idx] = row_ptr[r * (NODES + 1) + b * 64];
}

// phase 1: scatter (row,col) to bucket-contiguous regions (cursor-sequential writes)
__global__ void k_bucket(const int* __restrict__ edges, int* bcur, int2* __restrict__ ebuf) {
    int idx = blockIdx.x * blockDim.x + threadIdx.x;
    if (idx >= RELS * EDGES) return;
    int r = idx / EDGES;
    int e = idx - r * EDGES;
    const int* base = edges + (size_t)r * 2 * EDGES;
    int row = base[e];
    int col = base[EDGES + e];
    int pos = atomicAdd(&bcur[r * NBUCK + (row >> 6)], 1);
    ebuf[(size_t)r * EDGES + pos] = make_int2(row, col);
}

// phase 2: one block per bucket, LDS per-row cursors, L2-local csr_col writes
__global__ __launch_bounds__(256)
void k_place(const int2* __restrict__ ebuf, const int* __restrict__ row_ptr,
             int* __restrict__ csr_col) {
    int b = blockIdx.x;
    int r = blockIdx.y;
    int base_row = b * 64;
    __shared__ int cur[64];
    int t = threadIdx.x;
    const int* rp = row_ptr + r * (NODES + 1);
    if (t < 64) {
        int rr = base_row + t;
        cur[t] = (rr < NODES) ? rp[rr] : 0;
    }
    __syncthreads();
    int start = rp[base_row];
    int hi = base_row + 64; if (hi > NODES) hi = NODES;
    int end = rp[hi];
    const int2* eb = ebuf + (size_t)r * EDGES;
    int* cc = csr_col + (size_t)r * EDGES;
    for (int i = start + t; i < end; i += 256) {
        int2 ec = eb[i];
        int pos = atomicAdd(&cur[ec.x - base_row], 1);
        cc[pos] = ec.y;
    }
}

// ---------------- conversions ----------------

__global__ void k_f2bf(const float* __restrict__ src, unsigned short* __restrict__ dst, int count) {
    int i = blockIdx.x * blockDim.x + threadIdx.x;
    if (i < count) dst[i] = f2bf(src[i]);
}

// transpose+convert: W[r][k][n] fp32 -> Wt[r][n][k] bf16
__global__ void k_wt(const float* __restrict__ W, unsigned short* __restrict__ Wt) {
    int idx = blockIdx.x * blockDim.x + threadIdx.x;
    if (idx >= RELS * FEAT * FEAT) return;
    int r = idx >> 16;
    int rem = idx & 65535;
    int n = rem >> 8;
    int k = rem & 255;
    Wt[idx] = f2bf(W[(size_t)r * FEAT * FEAT + (size_t)k * FEAT + n]);
}

// ---------------- SPMM: wave per row, 2 edges per iteration, bf16 output ----------------

__global__ __launch_bounds__(256)
void k_spmm(const unsigned short* __restrict__ feat, const int* __restrict__ row_ptr,
            const int* __restrict__ csr_col, const float* __restrict__ dinv_row,
            const float* __restrict__ dinv_col, unsigned short* __restrict__ aggbf, int rel) {
    int wave = (blockIdx.x * blockDim.x + threadIdx.x) >> 6;
    int lane = threadIdx.x & 63;
    if (wave >= NODES) return;
    int row = wave;
    int half = lane >> 5;          // which edge of the pair
    int l32  = lane & 31;          // 16B chunk within the feature row
    int start = row_ptr[rel * (NODES + 1) + row];
    int end   = row_ptr[rel * (NODES + 1) + row + 1];
    const int* cols = csr_col + (size_t)rel * EDGES;
    const float* dc = dinv_col + rel * NODES;
    const unsigned short* fb = feat + l32 * 8;
    float acc[8] = {0.f, 0.f, 0.f, 0.f, 0.f, 0.f, 0.f, 0.f};
    for (int j = start + half; j < end; j += 2) {
        int col = cols[j];
        float wv = dc[col];
        u16x8 u = *(const u16x8*)(fb + (size_t)col * FEAT);
#pragma unroll
        for (int i = 0; i < 8; ++i) acc[i] += wv * bf2f(u[i]);
    }
#pragma unroll
    for (int i = 0; i < 8; ++i) acc[i] += __shfl_down(acc[i], 32, 64);
    if (half == 0) {
        float dr = dinv_row[rel * NODES + row];
        u16x8 o;
#pragma unroll
        for (int i = 0; i < 8; ++i) o[i] = f2bf(acc[i] * dr);
        *(u16x8*)(aggbf + (size_t)row * FEAT + l32 * 8) = o;
    }
}

// ---------------- MFMA GEMM core helpers ----------------
// 128x128 tile, BK=64, XOR-swizzled LDS (conflict-free ds_read_b128).
// C/D layout: col = lane&15, row = quad*4 + reg.

// Layer 1 fused: h1bf = bf16( sum_r 0.25*relu(agg_r @ W1t_r^T) )
__global__ __launch_bounds__(256)
void k_gemm1(const unsigned short* __restrict__ Abase, const unsigned short* __restrict__ Wt,
             unsigned short* __restrict__ h1bf) {
    __shared__ __align__(16) unsigned short As[128 * 64];
    __shared__ __align__(16) unsigned short Bs[128 * 64];
    int tid = threadIdx.x;
    int wave = tid >> 6, lane = tid & 63;
    int quad = lane >> 4, l16 = lane & 15;
    int wm = (wave & 1) * 64, wn = (wave >> 1) * 64;
    int row0 = blockIdx.x * 128, n0 = blockIdx.y * 128;

    f32x4 hacc[4][4];
#pragma unroll
    for (int mi = 0; mi < 4; ++mi)
#pragma unroll
        for (int ni = 0; ni < 4; ++ni)
            hacc[mi][ni] = (f32x4){0.f, 0.f, 0.f, 0.f};

    for (int r = 0; r < RELS; ++r) {
        const unsigned short* A  = Abase + (size_t)r * MPAD * FEAT;
        const unsigned short* Bt = Wt + (size_t)r * FEAT * FEAT;
        f32x4 acc[4][4];
#pragma unroll
        for (int mi = 0; mi < 4; ++mi)
#pragma unroll
            for (int ni = 0; ni < 4; ++ni)
                acc[mi][ni] = (f32x4){0.f, 0.f, 0.f, 0.f};

        for (int k0 = 0; k0 < FEAT; k0 += 64) {
#pragma unroll
            for (int issue = 0; issue < 4; ++issue) {
                int flat = issue * 256 + tid;
                int row = flat >> 3;
                int gr = flat & 7;
                int sg = gr ^ (row & 7);
                *(uint4*)&As[flat * 8] = *(const uint4*)(A + (size_t)(row0 + row) * FEAT + k0 + sg * 8);
                *(uint4*)&Bs[flat * 8] = *(const uint4*)(Bt + (size_t)(n0 + row) * FEAT + k0 + sg * 8);
            }
            __syncthreads();
#pragma unroll
            for (int ks = 0; ks < 2; ++ks) {
                int g = ks * 4 + quad;
                short8 af[4], bfr[4];
#pragma unroll
                for (int mi = 0; mi < 4; ++mi) {
                    int m = wm + mi * 16 + l16;
                    af[mi] = *(const short8*)&As[m * 64 + ((g ^ (m & 7)) << 3)];
                }
#pragma unroll
                for (int ni = 0; ni < 4; ++ni) {
                    int n = wn + ni * 16 + l16;
                    bfr[ni] = *(const short8*)&Bs[n * 64 + ((g ^ (n & 7)) << 3)];
                }
#pragma unroll
                for (int mi = 0; mi < 4; ++mi)
#pragma unroll
                    for (int ni = 0; ni < 4; ++ni)
                        acc[mi][ni] = __builtin_amdgcn_mfma_f32_16x16x32_bf16(af[mi], bfr[ni], acc[mi][ni], 0, 0, 0);
            }
            __syncthreads();
        }
#pragma unroll
        for (int mi = 0; mi < 4; ++mi)
#pragma unroll
            for (int ni = 0; ni < 4; ++ni)
#pragma unroll
                for (int i = 0; i < 4; ++i) {
                    float v = acc[mi][ni][i];
                    hacc[mi][ni][i] += 0.25f * (v > 0.f ? v : 0.f);
                }
    }

#pragma unroll
    for (int mi = 0; mi < 4; ++mi)
#pragma unroll
        for (int ni = 0; ni < 4; ++ni) {
            int col = n0 + wn + ni * 16 + l16;
#pragma unroll
            for (int i = 0; i < 4; ++i) {
                int row = row0 + wm + mi * 16 + quad * 4 + i;
                if (row < NODES) h1bf[(size_t)row * FEAT + col] = f2bf(hacc[mi][ni][i]);
            }
        }
}

// Layer 2: H2 = bf16(relu(agg @ W2t^T)) per relation
__global__ __launch_bounds__(256)
void k_gemm2(const unsigned short* __restrict__ A, const unsigned short* __restrict__ Bt,
             unsigned short* __restrict__ H2) {
    __shared__ __align__(16) unsigned short As[128 * 64];
    __shared__ __align__(16) unsigned short Bs[128 * 64];
    int tid = threadIdx.x;
    int wave = tid >> 6, lane = tid & 63;
    int quad = lane >> 4, l16 = lane & 15;
    int wm = (wave & 1) * 64, wn = (wave >> 1) * 64;
    int row0 = blockIdx.x * 128, n0 = blockIdx.y * 128;

    f32x4 acc[4][4];
#pragma unroll
    for (int mi = 0; mi < 4; ++mi)
#pragma unroll
        for (int ni = 0; ni < 4; ++ni)
            acc[mi][ni] = (f32x4){0.f, 0.f, 0.f, 0.f};

    for (int k0 = 0; k0 < FEAT; k0 += 64) {
#pragma unroll
        for (int issue = 0; issue < 4; ++issue) {
            int flat = issue * 256 + tid;
            int row = flat >> 3;
            int gr = flat & 7;
            int sg = gr ^ (row & 7);
            *(uint4*)&As[flat * 8] = *(const uint4*)(A + (size_t)(row0 + row) * FEAT + k0 + sg * 8);
            *(uint4*)&Bs[flat * 8] = *(const uint4*)(Bt + (size_t)(n0 + row) * FEAT + k0 + sg * 8);
        }
        __syncthreads();
#pragma unroll
        for (int ks = 0; ks < 2; ++ks) {
            int g = ks * 4 + quad;
            short8 af[4], bfr[4];
#pragma unroll
            for (int mi = 0; mi < 4; ++mi) {
                int m = wm + mi * 16 + l16;
                af[mi] = *(const short8*)&As[m * 64 + ((g ^ (m & 7)) << 3)];
            }
#pragma unroll
            for (int ni = 0; ni < 4; ++ni) {
                int n = wn + ni * 16 + l16;
                bfr[ni] = *(const short8*)&Bs[n * 64 + ((g ^ (n & 7)) << 3)];
            }
#pragma unroll
            for (int mi = 0; mi < 4; ++mi)
#pragma unroll
                for (int ni = 0; ni < 4; ++ni)
                    acc[mi][ni] = __builtin_amdgcn_mfma_f32_16x16x32_bf16(af[mi], bfr[ni], acc[mi][ni], 0, 0, 0);
        }
        __syncthreads();
    }

#pragma unroll
    for (int mi = 0; mi < 4; ++mi)
#pragma unroll
        for (int ni = 0; ni < 4; ++ni) {
            int col = n0 + wn + ni * 16 + l16;
#pragma unroll
            for (int i = 0; i < 4; ++i) {
                int row = row0 + wm + mi * 16 + quad * 4 + i;
                if (row < NODES) {
                    float v = acc[mi][ni][i];
                    H2[(size_t)row * FEAT + col] = f2bf(v > 0.f ? v : 0.f);
                }
            }
        }
}

// ---------------- attention scores + softmax (wave per node) ----------------

__global__ __launch_bounds__(256)
void k_scores(const unsigned short* __restrict__ H2bf, const float* __restrict__ att_q,
              const float* __restrict__ tau_p, float* __restrict__ alpha_out) {
    int wave = (blockIdx.x * blockDim.x + threadIdx.x) >> 6;
    int lane = threadIdx.x & 63;
    if (wave >= NODES) return;
    int n = wave;
    float4 q = *(const float4*)(att_q + lane * 4);
    float s[RELS];
#pragma unroll
    for (int r = 0; r < RELS; ++r) {
        ushort4 u = *(const ushort4*)(H2bf + ((size_t)r * NODES + n) * FEAT + lane * 4);
        s[r] = bf2f(u.x) * q.x + bf2f(u.y) * q.y + bf2f(u.z) * q.z + bf2f(u.w) * q.w;
    }
#pragma unroll
    for (int off = 32; off > 0; off >>= 1) {
#pragma unroll
        for (int r = 0; r < RELS; ++r) s[r] += __shfl_down(s[r], off, 64);
    }
    if (lane == 0) {
        float tau = tau_p[0];
        tau = fminf(fmaxf(tau, 0.5f), 5.0f);
        float it = 1.0f / tau;
        float m = fmaxf(fmaxf(s[0], s[1]), fmaxf(s[2], s[3]));
        float e0 = expf((s[0] - m) * it);
        float e1 = expf((s[1] - m) * it);
        float e2 = expf((s[2] - m) * it);
        float e3 = expf((s[3] - m) * it);
        float inv = 1.0f / (e0 + e1 + e2 + e3);
        float4 al = { e0 * inv, e1 * inv, e2 * inv, e3 * inv };
        *(float4*)(alpha_out + (size_t)n * 4) = al;
    }
}

// ---------------- fused h2-combine + output GEMM ----------------

__global__ __launch_bounds__(256)
void k_logits(const unsigned short* __restrict__ H2bf, const float* __restrict__ alpha,
              const float* __restrict__ W_out, const float* __restrict__ b_out,
              float* __restrict__ logits) {
    int gid = blockIdx.x * blockDim.x + threadIdx.x;
    if (gid >= NODES * NCLS) return;
    int n = gid >> 4;
    int c = gid & 15;
    float a0 = 0.25f + alpha[(size_t)n * 4 + 0];
    float a1 = 0.25f + alpha[(size_t)n * 4 + 1];
    float a2 = 0.25f + alpha[(size_t)n * 4 + 2];
    float a3 = 0.25f + alpha[(size_t)n * 4 + 3];
    const unsigned short* h0 = H2bf + (size_t)n * FEAT;
    const size_t rs = (size_t)NODES * FEAT;
    float acc = b_out[c];
#pragma unroll 4
    for (int h = 0; h < FEAT; ++h) {
        float h2 = a0 * bf2f(h0[h]) + a1 * bf2f(h0[h + rs]) +
                   a2 * bf2f(h0[h + 2 * rs]) + a3 * bf2f(h0[h + 3 * rs]);
        acc += h2 * W_out[h * NCLS + c];
    }
    logits[gid] = acc;
}

// ---------------- launcher ----------------

static inline int cdiv(int a, int b) { return (a + b - 1) / b; }

extern "C" void kernel_launch(void* const* d_in, const int* in_sizes, int n_in,
                              void* d_out, int out_size, void* d_ws, size_t ws_size,
                              hipStream_t stream) {
    const float* X     = (const float*)d_in[0];
    const int*   edges = (const int*)d_in[1];
    const float* W1    = (const float*)d_in[2];
    const float* W2    = (const float*)d_in[3];
    const float* att_q = (const float*)d_in[4];
    const float* tau   = (const float*)d_in[5];
    const float* W_out = (const float*)d_in[6];
    const float* b_out = (const float*)d_in[7];

    float* logits = (float*)d_out;
    float* alpha  = logits + (size_t)NODES * NCLS;

    char* p = (char*)d_ws;
    auto carve = [&](size_t bytes) -> char* {
        char* q = p;
        p += (bytes + 255) & ~(size_t)255;
        return q;
    };
    int*   deg_row  = (int*)carve((size_t)RELS * NODES * 4);
    int*   deg_col  = (int*)carve((size_t)RELS * NODES * 4);
    float* dinv_row = (float*)carve((size_t)RELS * NODES * 4);
    float* dinv_col = (float*)carve((size_t)RELS * NODES * 4);
    int*   row_ptr  = (int*)carve((size_t)RELS * (NODES + 1) * 4);
    int*   bcur     = (int*)carve((size_t)RELS * NBUCK * 4);
    int*   csr_col  = (int*)carve((size_t)RELS * EDGES * 4);
    unsigned short* Xbf  = (unsigned short*)carve((size_t)NODES * FEAT * 2);
    unsigned short* h1bf = (unsigned short*)carve((size_t)NODES * FEAT * 2);
    unsigned short* W1t  = (unsigned short*)carve((size_t)RELS * FEAT * FEAT * 2);
    unsigned short* W2t  = (unsigned short*)carve((size_t)RELS * FEAT * FEAT * 2);
    // BIG region, phase-aliased:
    //   phase A (CSR build): ebuf = 4*E int2 = 51.2 MB  (at BIG)
    //   phase B/C (layer 1): agg[r] = BIG + r*AGGS (4 slices, 102.5 MB)
    //   phase D/E (layer 2+): agg0 = BIG, H2bf = BIG + AGGS (102.4 MB)
    const size_t AGGS = (size_t)MPAD * FEAT * 2;                       // one agg slice
    char* BIG = carve(AGGS + (size_t)RELS * NODES * FEAT * 2);
    int2* ebuf = (int2*)BIG;
    unsigned short* aggbf = (unsigned short*)BIG;                      // 4 slices of AGGS
    unsigned short* H2bf  = (unsigned short*)(BIG + AGGS);

    hipMemsetAsync(deg_row, 0, (size_t)2 * RELS * NODES * 4, stream);

    // CSR build: hist -> dinv -> scan -> bucket-scatter -> place
    k_hist<<<cdiv(RELS * EDGES, 256), 256, 0, stream>>>(edges, deg_row, deg_col);
    k_dinv<<<cdiv(RELS * NODES, 256), 256, 0, stream>>>(deg_row, deg_col, dinv_row, dinv_col);
    k_scan<<<RELS, 1024, 0, stream>>>(deg_row, row_ptr);
    k_binit<<<cdiv(RELS * NBUCK, 256), 256, 0, stream>>>(row_ptr, bcur);
    k_bucket<<<cdiv(RELS * EDGES, 256), 256, 0, stream>>>(edges, bcur, ebuf);
    {
        dim3 pg(NBUCK, RELS);
        k_place<<<pg, 256, 0, stream>>>(ebuf, row_ptr, csr_col);
    }

    // conversions
    k_f2bf<<<cdiv(NODES * FEAT, 256), 256, 0, stream>>>(X, Xbf, NODES * FEAT);
    k_wt<<<cdiv(RELS * FEAT * FEAT, 256), 256, 0, stream>>>(W1, W1t);
    k_wt<<<cdiv(RELS * FEAT * FEAT, 256), 256, 0, stream>>>(W2, W2t);

    dim3 gemm_grid(MPAD / 128, FEAT / 128);

    // Layer 1: 4 SPMMs into 4 agg slices, then one fused GEMM -> h1bf
    for (int r = 0; r < RELS; ++r)
        k_spmm<<<cdiv(NODES * 64, 256), 256, 0, stream>>>(Xbf, row_ptr, csr_col,
                                                          dinv_row, dinv_col,
                                                          aggbf + (size_t)r * MPAD * FEAT, r);
    k_gemm1<<<gemm_grid, 256, 0, stream>>>(aggbf, W1t, h1bf);

    // Layer 2: per relation, SPMM into slice 0 then GEMM -> H2bf[r]
    for (int r = 0; r < RELS; ++r) {
        k_spmm<<<cdiv(NODES * 64, 256), 256, 0, stream>>>(h1bf, row_ptr, csr_col,
                                                          dinv_row, dinv_col, aggbf, r);
        k_gemm2<<<gemm_grid, 256, 0, stream>>>(aggbf, W2t + (size_t)r * FEAT * FEAT,
                                               H2bf + (size_t)r * NODES * FEAT);
    }

    // attention + output
    k_scores<<<cdiv(NODES * 64, 256), 256, 0, stream>>>(H2bf, att_q, tau, alpha);
    k_logits<<<cdiv(NODES * NCLS, 256), 256, 0, stream>>>(H2bf, alpha, W_out, b_out, logits);
}

// Round 4
// 2197.001 us; speedup vs baseline: 1.4854x; 1.4854x over previous
//
#include <hip/hip_runtime.h>
#include <hip/hip_bf16.h>
#include <stdint.h>

#define NODES 50000
#define RELS  4
#define EDGES 1600000
#define FEAT  256
#define NCLS  16
#define MPAD  50048                 // 391 * 128
#define RPS   50016                 // row_ptr per-relation stride (16-aligned)
#define SCHUNK 1024                 // scan elements per block
#define NSBLK  49                   // ceil(50000/1024)
#define FPASS  8                    // fill passes
#define FWIN   6250                 // rows per fill pass

typedef __attribute__((ext_vector_type(8))) short short8;
typedef __attribute__((ext_vector_type(8))) unsigned short u16x8;
typedef __attribute__((ext_vector_type(4))) float f32x4;

static __device__ __forceinline__ float bf2f(unsigned short u) {
    return __uint_as_float(((unsigned int)u) << 16);
}
static __device__ __forceinline__ unsigned short f2bf(float f) {
    unsigned int x = __float_as_uint(f);
    unsigned int r = x + 0x7fffu + ((x >> 16) & 1u);
    return (unsigned short)(r >> 16);
}

// ---------------- CSR build ----------------

__global__ void k_hist(const int* __restrict__ edges, int* deg_row, int* deg_col) {
    int idx = blockIdx.x * blockDim.x + threadIdx.x;
    if (idx >= RELS * EDGES) return;
    int r = idx / EDGES;
    int e = idx - r * EDGES;
    const int* base = edges + (size_t)r * 2 * EDGES;
    int row = base[e];
    int col = base[EDGES + e];
    atomicAdd(&deg_row[r * NODES + row], 1);
    atomicAdd(&deg_col[r * NODES + col], 1);
}

__global__ void k_dinv(const int* __restrict__ deg_row, const int* __restrict__ deg_col,
                       float* dinv_row, float* dinv_col) {
    int idx = blockIdx.x * blockDim.x + threadIdx.x;
    if (idx >= RELS * NODES) return;
    int dr = deg_row[idx]; if (dr < 1) dr = 1;
    int dc = deg_col[idx]; if (dc < 1) dc = 1;
    dinv_row[idx] = rsqrtf((float)dr);
    dinv_col[idx] = rsqrtf((float)dc);
}

// -------- parallel exclusive scan of deg_row -> row_ptr (3 kernels) --------
// A: per-block (1024 elems) local exclusive scan into tmp + block totals
__global__ __launch_bounds__(256)
void k_scanA(const int* __restrict__ deg, int* __restrict__ tmp, int* __restrict__ btot) {
    int r = blockIdx.y, blk = blockIdx.x, t = threadIdx.x;
    int i0 = blk * SCHUNK + t * 4;
    const int* d = deg + (size_t)r * NODES;
    int4 v = make_int4(0, 0, 0, 0);
    if (i0 + 3 < NODES) v = *(const int4*)(d + i0);
    else if (i0 < NODES) {
        v.x = d[i0];
        if (i0 + 1 < NODES) v.y = d[i0 + 1];
        if (i0 + 2 < NODES) v.z = d[i0 + 2];
    }
    int s = v.x + v.y + v.z + v.w;
    __shared__ int sh[256];
    sh[t] = s;
    __syncthreads();
    for (int off = 1; off < 256; off <<= 1) {
        int u = (t >= off) ? sh[t - off] : 0;
        __syncthreads();
        sh[t] += u;
        __syncthreads();
    }
    int excl = sh[t] - s;
    int4 o;
    o.x = excl; o.y = excl + v.x; o.z = o.y + v.y; o.w = o.z + v.z;
    int* tp = tmp + (size_t)r * NODES;
    if (i0 + 3 < NODES) *(int4*)(tp + i0) = o;
    else if (i0 < NODES) {
        tp[i0] = o.x;
        if (i0 + 1 < NODES) tp[i0 + 1] = o.y;
        if (i0 + 2 < NODES) tp[i0 + 2] = o.z;
    }
    if (t == 255) btot[r * 64 + blk] = sh[255];
}

// B: scan the 49 block totals per relation (serial, tiny)
__global__ void k_scanB(int* __restrict__ btot, int* __restrict__ row_ptr) {
    int r = blockIdx.x;
    if (threadIdx.x != 0) return;
    int acc = 0;
    for (int b = 0; b < NSBLK; ++b) {
        int v = btot[r * 64 + b];
        btot[r * 64 + b] = acc;
        acc += v;
    }
    row_ptr[r * RPS + NODES] = acc;
}

// C: add block offsets; writes row_ptr AND cursor (cursor aliases tmp in-place)
__global__ __launch_bounds__(256)
void k_scanC(int* __restrict__ tmp, const int* __restrict__ btot, int* __restrict__ row_ptr) {
    int r = blockIdx.y, blk = blockIdx.x, t = threadIdx.x;
    int i0 = blk * SCHUNK + t * 4;
    int off = btot[r * 64 + blk];
    int* tp = tmp + (size_t)r * NODES;
    int* rp = row_ptr + (size_t)r * RPS;
    if (i0 + 3 < NODES) {
        int4 v = *(const int4*)(tp + i0);
        v.x += off; v.y += off; v.z += off; v.w += off;
        *(int4*)(tp + i0) = v;              // cursor
        rp[i0] = v.x; rp[i0 + 1] = v.y; rp[i0 + 2] = v.z; rp[i0 + 3] = v.w;
    } else if (i0 < NODES) {
        for (int j = 0; j < 4 && i0 + j < NODES; ++j) {
            int v = tp[i0 + j] + off;
            tp[i0 + j] = v;
            rp[i0 + j] = v;
        }
    }
}

// fill pass: only rows in [lo, hi) — CSR writes land in a dense ~3 MB window
__global__ void k_fillp(const int* __restrict__ edges, int* cursor, int* __restrict__ csr_col,
                        int lo, int hi) {
    int idx = blockIdx.x * blockDim.x + threadIdx.x;
    if (idx >= RELS * EDGES) return;
    int r = idx / EDGES;
    int e = idx - r * EDGES;
    const int* base = edges + (size_t)r * 2 * EDGES;
    int row = base[e];
    if (row < lo || row >= hi) return;
    int col = base[EDGES + e];
    int pos = atomicAdd(&cursor[r * NODES + row], 1);
    csr_col[(size_t)r * EDGES + pos] = col;
}

// ---------------- conversions ----------------

__global__ void k_f2bf(const float* __restrict__ src, unsigned short* __restrict__ dst, int count) {
    int i = blockIdx.x * blockDim.x + threadIdx.x;
    if (i < count) dst[i] = f2bf(src[i]);
}

// transpose+convert: W[r][k][n] fp32 -> Wt[r][n][k] bf16
__global__ void k_wt(const float* __restrict__ W, unsigned short* __restrict__ Wt) {
    int idx = blockIdx.x * blockDim.x + threadIdx.x;
    if (idx >= RELS * FEAT * FEAT) return;
    int r = idx >> 16;
    int rem = idx & 65535;
    int n = rem >> 8;
    int k = rem & 255;
    Wt[idx] = f2bf(W[(size_t)r * FEAT * FEAT + (size_t)k * FEAT + n]);
}

// ---------------- SPMM: wave per row, 2 edges/iter, 2x unrolled, bf16 out ----------------

__global__ __launch_bounds__(256)
void k_spmm(const unsigned short* __restrict__ feat, const int* __restrict__ row_ptr,
            const int* __restrict__ csr_col, const float* __restrict__ dinv_row,
            const float* __restrict__ dinv_col, unsigned short* __restrict__ aggbf, int rel) {
    int wave = (blockIdx.x * blockDim.x + threadIdx.x) >> 6;
    int lane = threadIdx.x & 63;
    if (wave >= NODES) return;
    int row = wave;
    int half = lane >> 5;
    int l32  = lane & 31;
    int start = row_ptr[rel * RPS + row];
    int end   = row_ptr[rel * RPS + row + 1];
    const int* cols = csr_col + (size_t)rel * EDGES;
    const float* dc = dinv_col + rel * NODES;
    const unsigned short* fb = feat + l32 * 8;
    float acc[8] = {0.f, 0.f, 0.f, 0.f, 0.f, 0.f, 0.f, 0.f};
    int j = start + half;
    // unrolled: 2 edges per half in flight (4 per wave)
    for (; j + 2 < end; j += 4) {
        int c0 = cols[j];
        int c1 = cols[j + 2];
        float w0 = dc[c0];
        float w1 = dc[c1];
        u16x8 u0 = *(const u16x8*)(fb + (size_t)c0 * FEAT);
        u16x8 u1 = *(const u16x8*)(fb + (size_t)c1 * FEAT);
#pragma unroll
        for (int i = 0; i < 8; ++i) acc[i] += w0 * bf2f(u0[i]);
#pragma unroll
        for (int i = 0; i < 8; ++i) acc[i] += w1 * bf2f(u1[i]);
    }
    if (j < end) {
        int c0 = cols[j];
        float w0 = dc[c0];
        u16x8 u0 = *(const u16x8*)(fb + (size_t)c0 * FEAT);
#pragma unroll
        for (int i = 0; i < 8; ++i) acc[i] += w0 * bf2f(u0[i]);
    }
#pragma unroll
    for (int i = 0; i < 8; ++i) acc[i] += __shfl_down(acc[i], 32, 64);
    if (half == 0) {
        float dr = dinv_row[rel * NODES + row];
        u16x8 o;
#pragma unroll
        for (int i = 0; i < 8; ++i) o[i] = f2bf(acc[i] * dr);
        *(u16x8*)(aggbf + (size_t)row * FEAT + l32 * 8) = o;
    }
}

// ---------------- MFMA GEMM (128x128 tile, BK=64, XOR-swizzled LDS) ----------------
// C/D layout: col = lane&15, row = quad*4 + reg.

// Layer 1 fused: h1bf = bf16( sum_r 0.25*relu(agg_r @ W1t_r^T) )
__global__ __launch_bounds__(256)
void k_gemm1(const unsigned short* __restrict__ Abase, const unsigned short* __restrict__ Wt,
             unsigned short* __restrict__ h1bf) {
    __shared__ __align__(16) unsigned short As[128 * 64];
    __shared__ __align__(16) unsigned short Bs[128 * 64];
    int tid = threadIdx.x;
    int wave = tid >> 6, lane = tid & 63;
    int quad = lane >> 4, l16 = lane & 15;
    int wm = (wave & 1) * 64, wn = (wave >> 1) * 64;
    int row0 = blockIdx.x * 128, n0 = blockIdx.y * 128;

    f32x4 hacc[4][4];
#pragma unroll
    for (int mi = 0; mi < 4; ++mi)
#pragma unroll
        for (int ni = 0; ni < 4; ++ni)
            hacc[mi][ni] = (f32x4){0.f, 0.f, 0.f, 0.f};

    for (int r = 0; r < RELS; ++r) {
        const unsigned short* A  = Abase + (size_t)r * MPAD * FEAT;
        const unsigned short* Bt = Wt + (size_t)r * FEAT * FEAT;
        f32x4 acc[4][4];
#pragma unroll
        for (int mi = 0; mi < 4; ++mi)
#pragma unroll
            for (int ni = 0; ni < 4; ++ni)
                acc[mi][ni] = (f32x4){0.f, 0.f, 0.f, 0.f};

        for (int k0 = 0; k0 < FEAT; k0 += 64) {
#pragma unroll
            for (int issue = 0; issue < 4; ++issue) {
                int flat = issue * 256 + tid;
                int row = flat >> 3;
                int gr = flat & 7;
                int sg = gr ^ (row & 7);
                *(uint4*)&As[flat * 8] = *(const uint4*)(A + (size_t)(row0 + row) * FEAT + k0 + sg * 8);
                *(uint4*)&Bs[flat * 8] = *(const uint4*)(Bt + (size_t)(n0 + row) * FEAT + k0 + sg * 8);
            }
            __syncthreads();
#pragma unroll
            for (int ks = 0; ks < 2; ++ks) {
                int g = ks * 4 + quad;
                short8 af[4], bfr[4];
#pragma unroll
                for (int mi = 0; mi < 4; ++mi) {
                    int m = wm + mi * 16 + l16;
                    af[mi] = *(const short8*)&As[m * 64 + ((g ^ (m & 7)) << 3)];
                }
#pragma unroll
                for (int ni = 0; ni < 4; ++ni) {
                    int n = wn + ni * 16 + l16;
                    bfr[ni] = *(const short8*)&Bs[n * 64 + ((g ^ (n & 7)) << 3)];
                }
#pragma unroll
                for (int mi = 0; mi < 4; ++mi)
#pragma unroll
                    for (int ni = 0; ni < 4; ++ni)
                        acc[mi][ni] = __builtin_amdgcn_mfma_f32_16x16x32_bf16(af[mi], bfr[ni], acc[mi][ni], 0, 0, 0);
            }
            __syncthreads();
        }
#pragma unroll
        for (int mi = 0; mi < 4; ++mi)
#pragma unroll
            for (int ni = 0; ni < 4; ++ni)
#pragma unroll
                for (int i = 0; i < 4; ++i) {
                    float v = acc[mi][ni][i];
                    hacc[mi][ni][i] += 0.25f * (v > 0.f ? v : 0.f);
                }
    }

#pragma unroll
    for (int mi = 0; mi < 4; ++mi)
#pragma unroll
        for (int ni = 0; ni < 4; ++ni) {
            int col = n0 + wn + ni * 16 + l16;
#pragma unroll
            for (int i = 0; i < 4; ++i) {
                int row = row0 + wm + mi * 16 + quad * 4 + i;
                if (row < NODES) h1bf[(size_t)row * FEAT + col] = f2bf(hacc[mi][ni][i]);
            }
        }
}

// Layer 2: H2 = bf16(relu(agg @ W2t^T)) per relation
__global__ __launch_bounds__(256)
void k_gemm2(const unsigned short* __restrict__ A, const unsigned short* __restrict__ Bt,
             unsigned short* __restrict__ H2) {
    __shared__ __align__(16) unsigned short As[128 * 64];
    __shared__ __align__(16) unsigned short Bs[128 * 64];
    int tid = threadIdx.x;
    int wave = tid >> 6, lane = tid & 63;
    int quad = lane >> 4, l16 = lane & 15;
    int wm = (wave & 1) * 64, wn = (wave >> 1) * 64;
    int row0 = blockIdx.x * 128, n0 = blockIdx.y * 128;

    f32x4 acc[4][4];
#pragma unroll
    for (int mi = 0; mi < 4; ++mi)
#pragma unroll
        for (int ni = 0; ni < 4; ++ni)
            acc[mi][ni] = (f32x4){0.f, 0.f, 0.f, 0.f};

    for (int k0 = 0; k0 < FEAT; k0 += 64) {
#pragma unroll
        for (int issue = 0; issue < 4; ++issue) {
            int flat = issue * 256 + tid;
            int row = flat >> 3;
            int gr = flat & 7;
            int sg = gr ^ (row & 7);
            *(uint4*)&As[flat * 8] = *(const uint4*)(A + (size_t)(row0 + row) * FEAT + k0 + sg * 8);
            *(uint4*)&Bs[flat * 8] = *(const uint4*)(Bt + (size_t)(n0 + row) * FEAT + k0 + sg * 8);
        }
        __syncthreads();
#pragma unroll
        for (int ks = 0; ks < 2; ++ks) {
            int g = ks * 4 + quad;
            short8 af[4], bfr[4];
#pragma unroll
            for (int mi = 0; mi < 4; ++mi) {
                int m = wm + mi * 16 + l16;
                af[mi] = *(const short8*)&As[m * 64 + ((g ^ (m & 7)) << 3)];
            }
#pragma unroll
            for (int ni = 0; ni < 4; ++ni) {
                int n = wn + ni * 16 + l16;
                bfr[ni] = *(const short8*)&Bs[n * 64 + ((g ^ (n & 7)) << 3)];
            }
#pragma unroll
            for (int mi = 0; mi < 4; ++mi)
#pragma unroll
                for (int ni = 0; ni < 4; ++ni)
                    acc[mi][ni] = __builtin_amdgcn_mfma_f32_16x16x32_bf16(af[mi], bfr[ni], acc[mi][ni], 0, 0, 0);
        }
        __syncthreads();
    }

#pragma unroll
    for (int mi = 0; mi < 4; ++mi)
#pragma unroll
        for (int ni = 0; ni < 4; ++ni) {
            int col = n0 + wn + ni * 16 + l16;
#pragma unroll
            for (int i = 0; i < 4; ++i) {
                int row = row0 + wm + mi * 16 + quad * 4 + i;
                if (row < NODES) {
                    float v = acc[mi][ni][i];
                    H2[(size_t)row * FEAT + col] = f2bf(v > 0.f ? v : 0.f);
                }
            }
        }
}

// ---------------- attention scores + softmax (wave per node) ----------------

__global__ __launch_bounds__(256)
void k_scores(const unsigned short* __restrict__ H2bf, const float* __restrict__ att_q,
              const float* __restrict__ tau_p, float* __restrict__ alpha_out) {
    int wave = (blockIdx.x * blockDim.x + threadIdx.x) >> 6;
    int lane = threadIdx.x & 63;
    if (wave >= NODES) return;
    int n = wave;
    float4 q = *(const float4*)(att_q + lane * 4);
    float s[RELS];
#pragma unroll
    for (int r = 0; r < RELS; ++r) {
        ushort4 u = *(const ushort4*)(H2bf + ((size_t)r * NODES + n) * FEAT + lane * 4);
        s[r] = bf2f(u.x) * q.x + bf2f(u.y) * q.y + bf2f(u.z) * q.z + bf2f(u.w) * q.w;
    }
#pragma unroll
    for (int off = 32; off > 0; off >>= 1) {
#pragma unroll
        for (int r = 0; r < RELS; ++r) s[r] += __shfl_down(s[r], off, 64);
    }
    if (lane == 0) {
        float tau = tau_p[0];
        tau = fminf(fmaxf(tau, 0.5f), 5.0f);
        float it = 1.0f / tau;
        float m = fmaxf(fmaxf(s[0], s[1]), fmaxf(s[2], s[3]));
        float e0 = expf((s[0] - m) * it);
        float e1 = expf((s[1] - m) * it);
        float e2 = expf((s[2] - m) * it);
        float e3 = expf((s[3] - m) * it);
        float inv = 1.0f / (e0 + e1 + e2 + e3);
        float4 al = { e0 * inv, e1 * inv, e2 * inv, e3 * inv };
        *(float4*)(alpha_out + (size_t)n * 4) = al;
    }
}

// ---------------- fused h2-combine + output GEMM ----------------

__global__ __launch_bounds__(256)
void k_logits(const unsigned short* __restrict__ H2bf, const float* __restrict__ alpha,
              const float* __restrict__ W_out, const float* __restrict__ b_out,
              float* __restrict__ logits) {
    int gid = blockIdx.x * blockDim.x + threadIdx.x;
    if (gid >= NODES * NCLS) return;
    int n = gid >> 4;
    int c = gid & 15;
    float a0 = 0.25f + alpha[(size_t)n * 4 + 0];
    float a1 = 0.25f + alpha[(size_t)n * 4 + 1];
    float a2 = 0.25f + alpha[(size_t)n * 4 + 2];
    float a3 = 0.25f + alpha[(size_t)n * 4 + 3];
    const unsigned short* h0 = H2bf + (size_t)n * FEAT;
    const size_t rs = (size_t)NODES * FEAT;
    float acc = b_out[c];
#pragma unroll 4
    for (int h = 0; h < FEAT; ++h) {
        float h2 = a0 * bf2f(h0[h]) + a1 * bf2f(h0[h + rs]) +
                   a2 * bf2f(h0[h + 2 * rs]) + a3 * bf2f(h0[h + 3 * rs]);
        acc += h2 * W_out[h * NCLS + c];
    }
    logits[gid] = acc;
}

// ---------------- launcher ----------------

static inline int cdiv(int a, int b) { return (a + b - 1) / b; }

extern "C" void kernel_launch(void* const* d_in, const int* in_sizes, int n_in,
                              void* d_out, int out_size, void* d_ws, size_t ws_size,
                              hipStream_t stream) {
    const float* X     = (const float*)d_in[0];
    const int*   edges = (const int*)d_in[1];
    const float* W1    = (const float*)d_in[2];
    const float* W2    = (const float*)d_in[3];
    const float* att_q = (const float*)d_in[4];
    const float* tau   = (const float*)d_in[5];
    const float* W_out = (const float*)d_in[6];
    const float* b_out = (const float*)d_in[7];

    float* logits = (float*)d_out;
    float* alpha  = logits + (size_t)NODES * NCLS;

    char* p = (char*)d_ws;
    auto carve = [&](size_t bytes) -> char* {
        char* q = p;
        p += (bytes + 255) & ~(size_t)255;
        return q;
    };
    int*   deg_row  = (int*)carve((size_t)RELS * NODES * 4);
    int*   deg_col  = (int*)carve((size_t)RELS * NODES * 4);
    float* dinv_row = (float*)carve((size_t)RELS * NODES * 4);
    float* dinv_col = (float*)carve((size_t)RELS * NODES * 4);
    int*   row_ptr  = (int*)carve((size_t)RELS * RPS * 4 + 256);
    int*   cursor   = (int*)carve((size_t)RELS * NODES * 4);   // doubles as scan tmp
    int*   btot     = (int*)carve((size_t)RELS * 64 * 4);
    int*   csr_col  = (int*)carve((size_t)RELS * EDGES * 4);
    unsigned short* Xbf  = (unsigned short*)carve((size_t)NODES * FEAT * 2);
    unsigned short* h1bf = (unsigned short*)carve((size_t)NODES * FEAT * 2);
    unsigned short* W1t  = (unsigned short*)carve((size_t)RELS * FEAT * FEAT * 2);
    unsigned short* W2t  = (unsigned short*)carve((size_t)RELS * FEAT * FEAT * 2);
    // BIG region, phase-aliased:
    //   layer 1: agg[r] = BIG + r*AGGS (4 slices)
    //   layer 2: agg0 = BIG, H2bf = BIG + AGGS
    const size_t AGGS = (size_t)MPAD * FEAT * 2;
    char* BIG = carve(AGGS + (size_t)RELS * NODES * FEAT * 2);
    unsigned short* aggbf = (unsigned short*)BIG;
    unsigned short* H2bf  = (unsigned short*)(BIG + AGGS);

    hipMemsetAsync(deg_row, 0, (size_t)2 * RELS * NODES * 4, stream);

    // CSR build: hist -> dinv -> scan(A,B,C) -> 8 windowed fill passes
    k_hist<<<cdiv(RELS * EDGES, 256), 256, 0, stream>>>(edges, deg_row, deg_col);
    k_dinv<<<cdiv(RELS * NODES, 256), 256, 0, stream>>>(deg_row, deg_col, dinv_row, dinv_col);
    {
        dim3 sg(NSBLK, RELS);
        k_scanA<<<sg, 256, 0, stream>>>(deg_row, cursor, btot);
        k_scanB<<<RELS, 64, 0, stream>>>(btot, row_ptr);
        k_scanC<<<sg, 256, 0, stream>>>(cursor, btot, row_ptr);
    }
    for (int pass = 0; pass < FPASS; ++pass)
        k_fillp<<<cdiv(RELS * EDGES, 256), 256, 0, stream>>>(edges, cursor, csr_col,
                                                             pass * FWIN, (pass + 1) * FWIN);

    // conversions
    k_f2bf<<<cdiv(NODES * FEAT, 256), 256, 0, stream>>>(X, Xbf, NODES * FEAT);
    k_wt<<<cdiv(RELS * FEAT * FEAT, 256), 256, 0, stream>>>(W1, W1t);
    k_wt<<<cdiv(RELS * FEAT * FEAT, 256), 256, 0, stream>>>(W2, W2t);

    dim3 gemm_grid(MPAD / 128, FEAT / 128);

    // Layer 1: 4 SPMMs into 4 agg slices, then one fused GEMM -> h1bf
    for (int r = 0; r < RELS; ++r)
        k_spmm<<<cdiv(NODES * 64, 256), 256, 0, stream>>>(Xbf, row_ptr, csr_col,
                                                          dinv_row, dinv_col,
                                                          aggbf + (size_t)r * MPAD * FEAT, r);
    k_gemm1<<<gemm_grid, 256, 0, stream>>>(aggbf, W1t, h1bf);

    // Layer 2: per relation, SPMM into slice 0 then GEMM -> H2bf[r]
    for (int r = 0; r < RELS; ++r) {
        k_spmm<<<cdiv(NODES * 64, 256), 256, 0, stream>>>(h1bf, row_ptr, csr_col,
                                                          dinv_row, dinv_col, aggbf, r);
        k_gemm2<<<gemm_grid, 256, 0, stream>>>(aggbf, W2t + (size_t)r * FEAT * FEAT,
                                               H2bf + (size_t)r * NODES * FEAT);
    }

    // attention + output
    k_scores<<<cdiv(NODES * 64, 256), 256, 0, stream>>>(H2bf, att_q, tau, alpha);
    k_logits<<<cdiv(NODES * NCLS, 256), 256, 0, stream>>>(H2bf, alpha, W_out, b_out, logits);
}